// Round 4
// baseline (70.117 us; speedup 1.0000x reference)
//
#include <hip/hip_runtime.h>

// Chamfer-style 3-level loss. P=128 polygons, N=128 pred pts, M=1024 gt pts.
// Round-7: retry of R6's no-workspace single-main-dispatch design, with the
// hipMemsetAsync (the only unproven API element; container failed twice)
// replaced by a 1-thread init kernel. Design rationale unchanged:
// R0 (2 dispatches + ws) = 68.2us and R2 (same structure, register-resident
// phase 1) = 68.0us -- a large phase-1 rewrite moved wall time 0us, and the
// rocprof top-5 in both rounds is ONLY the harness's 268 MB d_ws poison fills
// (~40us each, 84% HBM peak). Theory: wall time = ws poison (+WAW dependency)
// + dispatch structure, not our math (~5-10us device, never in top-5).
// This kernel touches ZERO workspace bytes: init zeroes out[0], main does
// 256 blocks x 768 threads (3 (poly,half) units/block, 12 waves/CU), one
// atomicAdd per block (256 atomics ~26ns -> ~7us tail, mostly overlapped).
// Per-point math and min-tree bit-identical to the absmax==0 version; only
// the cross-block sum order changes (atomic order; prior session's atomic
// variants passed the absmax gate).
#define NPOLY 128
#define NPTS  128
#define NGT   1024
#define NBLK  256                // 1 block per CU
#define NTHR  768                // 12 waves; 24 groups of 32 lanes; 3 units

__global__ void init_out_kernel(float* __restrict__ out) {
    out[0] = 0.0f;
}

__global__ __launch_bounds__(NTHR) void chamfer_one_kernel(
    const float* __restrict__ pred0,
    const float* __restrict__ pred1,
    const float* __restrict__ pred2,
    const float* __restrict__ gt,
    float* __restrict__ out) {
    __shared__ float wave_sums[12];

    const int t = threadIdx.x;
    const int s = t & 31;        // gt slice within the 32-lane group
    const int g = t >> 5;        // group 0..23; 8 groups per unit

    // Unit = (level<<8) | (poly<<1) | half. 3 consecutive units per block.
    const int unit  = blockIdx.x * 3 + (g >> 3);
    const int half  = unit & 1;
    const int poly  = (unit >> 1) & (NPOLY - 1);
    const int level = unit >> 8;

    const float* pred = (level == 0) ? pred0 : ((level == 1) ? pred1 : pred2);
    const float  w    = (level == 0) ? 0.2f : ((level == 1) ? 0.3f : 0.5f);

    // gt point-pairs straight from global (1 MB total -> L2-resident).
    // Same slice order as the absmax==0 version: slice s scans pairs j*32+s.
    const float4* gsrc = (const float4*)(gt + (size_t)poly * (NGT * 2));

    // 16 independent global_load_dwordx4 in flight.
    float4 gq[16];
#pragma unroll
    for (int j = 0; j < 16; ++j) gq[j] = gsrc[(j << 5) + s];

    // This group's 8 pred points: coords [1:3] of [P,N,3]; 32-lane broadcast.
    float px[8], py[8], dmin[8];
#pragma unroll
    for (int p = 0; p < 8; ++p) {
        const float* pp =
            pred + ((size_t)poly * NPTS + half * 64 + (g & 7) * 8 + p) * 3 + 1;
        px[p]   = pp[0];
        py[p]   = pp[1];
        dmin[p] = 1e30f;
    }

    // 16 gt-pairs x 8 points per iteration; FP ops identical to the
    // absmax==0 version.
#pragma unroll
    for (int j = 0; j < 16; ++j) {
        float4 gq_j = gq[j];
#pragma unroll
        for (int p = 0; p < 8; ++p) {
            float dx0 = px[p] - gq_j.x, dy0 = py[p] - gq_j.y;
            float d0  = fmaf(dx0, dx0, dy0 * dy0);
            float dx1 = px[p] - gq_j.z, dy1 = py[p] - gq_j.w;
            float d1  = fmaf(dx1, dx1, dy1 * dy1);
            dmin[p] = fminf(dmin[p], fminf(d0, d1));
        }
    }

    // Min across the 32 slices (same butterfly as before).
#pragma unroll
    for (int o = 1; o <= 16; o <<= 1) {
#pragma unroll
        for (int p = 0; p < 8; ++p)
            dmin[p] = fminf(dmin[p], __shfl_xor(dmin[p], o));
    }

    // sqrt AFTER the full min (monotone -> same selection as reference).
    float d = 0.0f;
#pragma unroll
    for (int p = 0; p < 8; ++p) d += sqrtf(dmin[p]);

    // Partner group in this wave (same unit: 4 waves per unit, no straddle).
    d += __shfl_xor(d, 32);

    // Weight is uniform per wave (waves never straddle units).
    if ((t & 63) == 0) wave_sums[t >> 6] = d * w;
    __syncthreads();

    if (t == 0) {
        float total = 0.0f;
#pragma unroll
        for (int i = 0; i < 12; ++i) total += wave_sums[i];
        atomicAdd(out, total * (1.0f / (3.0f * NPOLY * NPTS)));
    }
}

extern "C" void kernel_launch(void* const* d_in, const int* in_sizes, int n_in,
                              void* d_out, int out_size, void* d_ws, size_t ws_size,
                              hipStream_t stream) {
    const float* pred0 = (const float*)d_in[0];
    const float* pred1 = (const float*)d_in[1];
    const float* pred2 = (const float*)d_in[2];
    const float* gt    = (const float*)d_in[3];
    float* out = (float*)d_out;

    init_out_kernel<<<1, 1, 0, stream>>>(out);
    chamfer_one_kernel<<<NBLK, NTHR, 0, stream>>>(pred0, pred1, pred2, gt, out);
}